// Round 3
// baseline (159.804 us; speedup 1.0000x reference)
//
#include <hip/hip_runtime.h>
#include <hip/hip_bf16.h>

#define NB 16384     // rows (B)
#define NC 1000      // classes (C)
#define NV (NC / 4)  // float4 per row = 250
// per-wave layout: lane l, chunk c (0..3) -> float4 index c*64+l (valid if <250)

__global__ __launch_bounds__(256) void ranking_loss_kernel(
        const float* __restrict__ logits,
        const float* __restrict__ target,
        float* __restrict__ partial) {
    const int t    = threadIdx.x;
    const int wave = t >> 6;
    const int lane = t & 63;
    const int row  = blockIdx.x * 4 + wave;

    const float4* __restrict__ t4 = (const float4*)(target + (size_t)row * NC);
    const float4* __restrict__ l4 = (const float4*)(logits + (size_t)row * NC);

    // ---- 8 independent loads in flight per lane ----
    float4 tv[4], lv[4];
    bool valid[4];
    #pragma unroll
    for (int c = 0; c < 4; ++c) {
        const int idx = c * 64 + lane;
        valid[c] = (idx < NV);
        tv[c] = make_float4(0.f, 0.f, 0.f, 0.f);
        lv[c] = make_float4(0.f, 0.f, 0.f, 0.f);
        if (valid[c]) {
            tv[c] = t4[idx];
            lv[c] = l4[idx];
        }
    }

    // ---- argmax(target row), first-index tie-break, butterfly so all lanes get it
    float bv = -INFINITY;
    int   bi = NC;
    #pragma unroll
    for (int c = 0; c < 4; ++c) {
        if (valid[c]) {
            const int base = (c * 64 + lane) * 4;
            float vals[4] = {tv[c].x, tv[c].y, tv[c].z, tv[c].w};
            #pragma unroll
            for (int k = 0; k < 4; ++k) {
                if (vals[k] > bv) { bv = vals[k]; bi = base + k; }
            }
        }
    }
    #pragma unroll
    for (int off = 1; off < 64; off <<= 1) {
        float ov = __shfl_xor(bv, off, 64);
        int   oi = __shfl_xor(bi, off, 64);
        if (ov > bv || (ov == bv && oi < bi)) { bv = ov; bi = oi; }
    }
    const int label = bi;   // wave-uniform now

    // ---- x1 = logits[row, label], extracted from registers via shuffle ----
    const int v4       = label >> 2;        // which float4
    const int src_lane = v4 & 63;           // lane that holds it
    const int chunk    = v4 >> 6;           // which of that lane's 4 chunks
    const int comp     = label & 3;
    float4 f = (chunk == 0) ? lv[0] : (chunk == 1) ? lv[1]
             : (chunk == 2) ? lv[2] : lv[3];
    float cand = (comp == 0) ? f.x : (comp == 1) ? f.y
               : (comp == 2) ? f.z : f.w;
    const float x1 = __shfl(cand, src_lane, 64);

    // ---- hinge-term sum from registers ----
    const float inv_pos = 1.0f / (float)(NC - 1);
    float sum = 0.0f;
    #pragma unroll
    for (int c = 0; c < 4; ++c) {
        if (valid[c]) {
            const int base = (c * 64 + lane) * 4;
            float vals[4] = {lv[c].x, lv[c].y, lv[c].z, lv[c].w};
            #pragma unroll
            for (int k = 0; k < 4; ++k) {
                const int j = base + k;
                // j==0: negative-class term, margin = 1.0 (NEG_MARGIN=1)
                const float margin = (j == 0) ? 1.0f
                                              : fabsf((float)(label - j)) * inv_pos;
                sum += fmaxf(vals[k] - x1 + margin, 0.0f);
            }
        }
    }
    #pragma unroll
    for (int off = 32; off > 0; off >>= 1)
        sum += __shfl_down(sum, off, 64);

    if (lane == 0)
        partial[row] = (label != 0) ? sum * (1.0f / (float)NB) : 0.0f;
}

// Sum 16384 partials -> out[0]. One block, 256 threads, float4 loads.
__global__ __launch_bounds__(256) void reduce_partials_kernel(
        const float* __restrict__ partial,
        float* __restrict__ out) {
    const int t    = threadIdx.x;
    const int wave = t >> 6;
    const int lane = t & 63;

    float sum = 0.0f;
    const float4* p4 = (const float4*)partial;
    #pragma unroll
    for (int i = 0; i < 16; ++i) {
        float4 v = p4[t + i * 256];
        sum += (v.x + v.y) + (v.z + v.w);
    }
    #pragma unroll
    for (int off = 32; off > 0; off >>= 1)
        sum += __shfl_down(sum, off, 64);

    __shared__ float s_sum[4];
    if (lane == 0) s_sum[wave] = sum;
    __syncthreads();
    if (t == 0)
        out[0] = s_sum[0] + s_sum[1] + s_sum[2] + s_sum[3];
}

extern "C" void kernel_launch(void* const* d_in, const int* in_sizes, int n_in,
                              void* d_out, int out_size, void* d_ws, size_t ws_size,
                              hipStream_t stream) {
    const float* logits = (const float*)d_in[0];
    const float* target = (const float*)d_in[1];
    float* out     = (float*)d_out;
    float* partial = (float*)d_ws;   // NB floats = 64 KB scratch

    ranking_loss_kernel<<<NB / 4, 256, 0, stream>>>(logits, target, partial);
    reduce_partials_kernel<<<1, 256, 0, stream>>>(partial, out);
}

// Round 4
// 142.299 us; speedup vs baseline: 1.1230x; 1.1230x over previous
//
#include <hip/hip_runtime.h>
#include <hip/hip_bf16.h>

#define NB 16384     // rows (B)
#define NC 1000      // classes (C)
#define NV (NC / 4)  // float4 per row = 250
// wave-per-row: lane l holds float4 indices {l, 64+l, 128+l, min(192+l,249)}

__global__ __launch_bounds__(256) void ranking_loss_kernel(
        const float* __restrict__ logits,
        const float* __restrict__ target,
        float* __restrict__ partial) {
    const int t    = threadIdx.x;
    const int wave = t >> 6;
    const int lane = t & 63;
    const int row  = blockIdx.x * 4 + wave;

    const float4* __restrict__ t4 = (const float4*)(target + (size_t)row * NC);
    const float4* __restrict__ l4 = (const float4*)(logits + (size_t)row * NC);

    const int  i0 = lane;
    const int  i1 = 64 + lane;
    const int  i2 = 128 + lane;
    const int  i3raw = 192 + lane;
    const int  i3 = (i3raw < NV) ? i3raw : (NV - 1);  // clamp: uniform flow
    const bool v3 = (i3raw < NV);                     // lanes 0..57 valid

    // ---- 8 unconditional loads, all in flight, no arrays (stay in VGPRs) ----
    float4 tv0 = t4[i0], tv1 = t4[i1], tv2 = t4[i2], tv3 = t4[i3];
    float4 lv0 = l4[i0], lv1 = l4[i1], lv2 = l4[i2], lv3 = l4[i3];

    // ---- argmax(target row), first-index tie-break, butterfly ----
    float bv = -INFINITY;
    int   bi = NC;
#define ARGMAX_F4(V, BASE)                                            \
    {                                                                 \
        const int base_ = (BASE);                                     \
        if (V.x > bv) { bv = V.x; bi = base_ + 0; }                   \
        if (V.y > bv) { bv = V.y; bi = base_ + 1; }                   \
        if (V.z > bv) { bv = V.z; bi = base_ + 2; }                   \
        if (V.w > bv) { bv = V.w; bi = base_ + 3; }                   \
    }
    ARGMAX_F4(tv0, i0 * 4)
    ARGMAX_F4(tv1, i1 * 4)
    ARGMAX_F4(tv2, i2 * 4)
    if (v3) ARGMAX_F4(tv3, i3 * 4)
#undef ARGMAX_F4

    #pragma unroll
    for (int off = 1; off < 64; off <<= 1) {
        float ov = __shfl_xor(bv, off, 64);
        int   oi = __shfl_xor(bi, off, 64);
        if (ov > bv || (ov == bv && oi < bi)) { bv = ov; bi = oi; }
    }
    const int label = bi;   // wave-uniform

    // ---- x1 = logits[row, label] from registers (uniform select + shuffle) ----
    const int v4       = label >> 2;   // which float4 (0..249)
    const int src_lane = v4 & 63;
    const int chunk    = v4 >> 6;      // 0..3 (wave-uniform)
    const int comp     = label & 3;    // wave-uniform
    float4 f = (chunk == 0) ? lv0 : (chunk == 1) ? lv1
             : (chunk == 2) ? lv2 : lv3;
    float cand = (comp == 0) ? f.x : (comp == 1) ? f.y
               : (comp == 2) ? f.z : f.w;
    const float x1 = __shfl(cand, src_lane, 64);

    // ---- hinge-term sum from registers ----
    const float inv_pos = 1.0f / (float)(NC - 1);
    float sum = 0.0f;
#define HINGE_F4(V, BASE)                                                        \
    {                                                                            \
        const int base_ = (BASE);                                                \
        {   /* j == 0 -> margin 1.0 (negative-class term, NEG_MARGIN=1) */       \
            float m0 = (base_ == 0) ? 1.0f : fabsf((float)(label - base_)) * inv_pos; \
            sum += fmaxf(V.x - x1 + m0, 0.0f);                                   \
        }                                                                        \
        sum += fmaxf(V.y - x1 + fabsf((float)(label - (base_ + 1))) * inv_pos, 0.0f); \
        sum += fmaxf(V.z - x1 + fabsf((float)(label - (base_ + 2))) * inv_pos, 0.0f); \
        sum += fmaxf(V.w - x1 + fabsf((float)(label - (base_ + 3))) * inv_pos, 0.0f); \
    }
    HINGE_F4(lv0, i0 * 4)
    HINGE_F4(lv1, i1 * 4)
    HINGE_F4(lv2, i2 * 4)
    if (v3) HINGE_F4(lv3, i3 * 4)
#undef HINGE_F4

    #pragma unroll
    for (int off = 32; off > 0; off >>= 1)
        sum += __shfl_down(sum, off, 64);

    if (lane == 0)
        partial[row] = (label != 0) ? sum * (1.0f / (float)NB) : 0.0f;
}

// Sum 16384 partials -> out[0]. One block, 256 threads, float4 loads.
__global__ __launch_bounds__(256) void reduce_partials_kernel(
        const float* __restrict__ partial,
        float* __restrict__ out) {
    const int t    = threadIdx.x;
    const int wave = t >> 6;
    const int lane = t & 63;

    float sum = 0.0f;
    const float4* p4 = (const float4*)partial;
    #pragma unroll
    for (int i = 0; i < 16; ++i) {
        float4 v = p4[t + i * 256];
        sum += (v.x + v.y) + (v.z + v.w);
    }
    #pragma unroll
    for (int off = 32; off > 0; off >>= 1)
        sum += __shfl_down(sum, off, 64);

    __shared__ float s_sum[4];
    if (lane == 0) s_sum[wave] = sum;
    __syncthreads();
    if (t == 0)
        out[0] = s_sum[0] + s_sum[1] + s_sum[2] + s_sum[3];
}

extern "C" void kernel_launch(void* const* d_in, const int* in_sizes, int n_in,
                              void* d_out, int out_size, void* d_ws, size_t ws_size,
                              hipStream_t stream) {
    const float* logits = (const float*)d_in[0];
    const float* target = (const float*)d_in[1];
    float* out     = (float*)d_out;
    float* partial = (float*)d_ws;   // NB floats = 64 KB scratch

    ranking_loss_kernel<<<NB / 4, 256, 0, stream>>>(logits, target, partial);
    reduce_partials_kernel<<<1, 256, 0, stream>>>(partial, out);
}